// Round 15
// baseline (1448.268 us; speedup 1.0000x reference)
//
#include <hip/hip_runtime.h>
#include <cstdint>

typedef _Float16 f16;
typedef _Float16 f16x4v __attribute__((ext_vector_type(4)));
typedef _Float16 f16x8 __attribute__((ext_vector_type(8)));
typedef float f32x4 __attribute__((ext_vector_type(4)));

#define DEV static __device__ __forceinline__

// async global->LDS, 16B per lane; LDS dest = wave-uniform base + lane*16
#define GLDS16(gp, lp) __builtin_amdgcn_global_load_lds( \
    (const __attribute__((address_space(1))) void*)(gp), \
    (__attribute__((address_space(3))) void*)(lp), 16, 0, 0)

DEV float sigf(float x) { return 1.0f / (1.0f + __expf(-x)); }
DEV float tanh2(float x) {
  float e = __expf(-2.0f * fabsf(x));
  float t = (1.0f - e) / (1.0f + e);
  return x >= 0.0f ? t : -t;
}

// one wave polls 64 contiguous producer flags (1 dword per lane, agent-scope)
DEV void waitflags(const unsigned* fp, int l) {
  unsigned f;
  do {
    f = __hip_atomic_load(fp + l, __ATOMIC_RELAXED, __HIP_MEMORY_SCOPE_AGENT);
  } while (__any(f == 0));
  asm volatile("" ::: "memory");
  __builtin_amdgcn_sched_barrier(0);
}

// poll one counter until >= want (wave-uniform broadcast load)
DEV void waitcnt_ge(const unsigned* cp, unsigned want) {
  unsigned c;
  do {
    c = __hip_atomic_load(cp, __ATOMIC_RELAXED, __HIP_MEMORY_SCOPE_AGENT);
  } while (__any(c < want));
  asm volatile("" ::: "memory");
  __builtin_amdgcn_sched_barrier(0);
}

// ---------------- merged fp32 -> fp16 convert (5 segments) ------------------
// segs 0,1: x (rows b*64+t) -> xt (rows t*32+b), transposed row order
__global__ __launch_bounds__(256) void k_cvt_all(
    const float* __restrict__ s0, f16* __restrict__ d0,
    const float* __restrict__ s1, f16* __restrict__ d1,
    const float* __restrict__ s2, f16* __restrict__ d2,
    const float* __restrict__ s3, f16* __restrict__ d3,
    const float* __restrict__ s4, f16* __restrict__ d4) {
  int bid = blockIdx.x;
  const float* s; f16* d; int base; int xpose = 0;
  if (bid < 4096)       { s = s0; d = d0; base = bid; xpose = 1; }
  else if (bid < 8192)  { s = s1; d = d1; base = bid - 4096; xpose = 1; }
  else if (bid < 10240) { s = s2; d = d2; base = bid - 8192; }
  else if (bid < 11264) { s = s3; d = d3; base = bid - 10240; }
  else                  { s = s4; d = d4; base = bid - 11264; }
  int i = (base * 256 + threadIdx.x) * 4;
  float4 v = *(const float4*)(s + i);
  f16x4v o;
  o.x = (f16)v.x; o.y = (f16)v.y; o.z = (f16)v.z; o.w = (f16)v.w;
  if (xpose) {
    int row = i >> 11, c = i & 2047;
    int orow = ((row & 63) << 5) | (row >> 6);   // (b*64+t) -> (t*32+b)
    *(f16x4v*)(d + (size_t)orow * 2048 + c) = o;
  } else {
    *(f16x4v*)(d + i) = o;
  }
}

// ---------------- pack Whh (4096x1024 fp32), K=1024 (kt 0..31) -------------
__global__ __launch_bounds__(256) void k_packw1(const float* __restrict__ Wa,
                                                const float* __restrict__ Wm,
                                                f16* __restrict__ Pa,
                                                f16* __restrict__ Pm) {
  const float* W = blockIdx.y ? Wm : Wa;
  f16* P = blockIdx.y ? Pm : Pa;
  int i2 = blockIdx.x * 256 + threadIdx.x;
  int l = i2 & 63, frag = i2 >> 6;
  int kt = frag & 31, ug = frag >> 5;
  int gate = ug & 3, ut = ug >> 2;
  int row = gate * 1024 + ut * 16 + (l & 15);
  int k = kt * 32 + 8 * (l >> 4);
  const float* s = W + row * 1024 + k;
  f16x8 o;
#pragma unroll
  for (int j = 0; j < 8; ++j) o[j] = (f16)s[j];
  *(f16x8*)(P + frag * 512 + l * 8) = o;
}

// ---------------- pack [Wih_2 | Whh_2] as K=2048 (kt 0..63) ----------------
__global__ __launch_bounds__(256) void k_packw2(const float* __restrict__ Wiha,
                                                const float* __restrict__ Whha,
                                                const float* __restrict__ Wihm,
                                                const float* __restrict__ Whhm,
                                                f16* __restrict__ Pa,
                                                f16* __restrict__ Pm) {
  const float* Wih = blockIdx.y ? Wihm : Wiha;
  const float* Whh = blockIdx.y ? Whhm : Whha;
  f16* P = blockIdx.y ? Pm : Pa;
  int i2 = blockIdx.x * 256 + threadIdx.x;
  int l = i2 & 63, frag = i2 >> 6;
  int kt = frag & 63, ug = frag >> 6;
  int gate = ug & 3, ut = ug >> 2;
  int row = gate * 1024 + ut * 16 + (l & 15);
  int k = kt * 32 + 8 * (l >> 4);
  const float* s = (k < 1024) ? (Wih + row * 1024 + k)
                              : (Whh + row * 1024 + (k - 1024));
  f16x8 o;
#pragma unroll
  for (int j = 0; j < 8; ++j) o[j] = (f16)s[j];
  *(f16x8*)(P + frag * 512 + l * 8) = o;
}

// shared-memory overlays (single 70KB block; roles use disjoint views)
struct ScanSm { float red[8][64][33]; f16 Gs[32][4][16]; };
struct GemmSm { f16 As[2][64 * 64]; f16 Bs[2][128 * 64]; };

// ---------------- fused dataflow kernel -------------------------------------
// 384 blocks x 512 thr: 0..127 = G0-GEMM producers (2 x 4-wave tile groups,
// 64x128 tiles, 8 rounds, early-t jobs first; agent-coherent C stores; gcnt
// counter per (s, t-pair)); 128..255 = cell1 (polls gcnt + flags1);
// 256..383 = cell2 (polls flags1/flags2; h2 feedback via t-major HaHm).
// Block ordering guarantees forward progress in both 1- and 2-block/CU
// regimes: gemm+cell1 = first 256 block IDs; gemm blocks retire.
__global__ __launch_bounds__(512, 1) void k_scan2(
    const f16* __restrict__ Wp1_a, const f16* __restrict__ Wp1_m,
    const f16* __restrict__ Wp2_a, const f16* __restrict__ Wp2_m,
    const f16* __restrict__ xt_a, const f16* __restrict__ xt_m,
    const float* __restrict__ W1f_a, const float* __restrict__ W1f_m,
    const float* __restrict__ bi1_a, const float* __restrict__ bh1_a,
    const float* __restrict__ bi1_m, const float* __restrict__ bh1_m,
    const float* __restrict__ bi2_a, const float* __restrict__ bh2_a,
    const float* __restrict__ bi2_m, const float* __restrict__ bh2_m,
    f16* __restrict__ G0a, f16* __restrict__ G0m,   // [t*32+b][4096]
    f16* __restrict__ H1h,            // [s][t][b][u] 2x64x32x1024
    f16* __restrict__ HaHm,           // [(t*32+b)][2048], s*1024 col offset
    unsigned* __restrict__ flags1,    // [s][t][64] dwords, zeroed
    unsigned* __restrict__ flags2,    // [s][t][64] dwords, zeroed
    unsigned* __restrict__ gcnt) {    // [s][32] t-pair counters, zeroed
  int bi = blockIdx.x;
  int tid = threadIdx.x, l = tid & 63, w = tid >> 6;   // w in [0,8)
  int lr = l & 15, lg = l >> 4;
  __shared__ alignas(16) char smem[sizeof(ScanSm)];

  if (bi < 128) {
    // ==================== role G: G0 = xt @ Wih_1^T + b1 ====================
    GemmSm* gs = (GemmSm*)smem;
    int g2 = w >> 2;                 // 4-wave group 0/1
    int tid2 = tid & 255;
    int w4 = tid2 >> 6;              // wave in group
    f16* As = gs->As[g2];
    f16* Bs = gs->Bs[g2];
    int wm4 = (w4 >> 1) * 32, wn4 = (w4 & 1) * 64;
    int sc = (l & 7) * 8;
    int br = tid2 >> 1, bh = tid2 & 1;
    for (int r2 = 0; r2 < 8; ++r2) {
      int job = r2 * 256 + bi * 2 + g2;   // jobs 0..2047, t-pair-major
      int mt_ = job >> 6, rem = job & 63;
      int sj = rem >> 5, ntile = rem & 31;
      const f16* A = sj ? xt_m : xt_a;
      const float* Bw = sj ? W1f_m : W1f_a;
      const float* b1i = sj ? bi1_m : bi1_a;
      const float* b1h = sj ? bh1_m : bh1_a;
      f16* C = sj ? G0m : G0a;
      int m0 = mt_ * 64, n0 = ntile * 128;

      f32x4 acc[2][4];
      f32x4 zero = {0.f, 0.f, 0.f, 0.f};
#pragma unroll
      for (int mt = 0; mt < 2; ++mt)
#pragma unroll
        for (int nt = 0; nt < 4; ++nt) acc[mt][nt] = zero;

      for (int kt = 0; kt < 32; ++kt) {
        int k0 = kt * 64;
#pragma unroll
        for (int c2 = 0; c2 < 2; ++c2)
          GLDS16(A + (size_t)(m0 + w4 * 16 + c2 * 8 + (l >> 3)) * 2048 + k0 + sc,
                 As + (w4 * 16 + c2 * 8) * 64);
        float4 bv[8];
#pragma unroll
        for (int j = 0; j < 8; ++j)
          bv[j] = *(const float4*)(Bw + (size_t)(n0 + br) * 2048 + k0 + bh * 32 + j * 4);
#pragma unroll
        for (int j = 0; j < 8; ++j) {
          f16x4v c4;
          c4.x = (f16)bv[j].x; c4.y = (f16)bv[j].y;
          c4.z = (f16)bv[j].z; c4.w = (f16)bv[j].w;
          *(f16x4v*)(Bs + br * 64 + bh * 32 + j * 4) = c4;
        }
        __syncthreads();
#pragma unroll
        for (int ks = 0; ks < 2; ++ks) {
          f16x8 af[2], bf[4];
#pragma unroll
          for (int mt = 0; mt < 2; ++mt)
            af[mt] = *(const f16x8*)&As[(wm4 + mt * 16 + lr) * 64 + ks * 32 + 8 * lg];
#pragma unroll
          for (int nt = 0; nt < 4; ++nt)
            bf[nt] = *(const f16x8*)&Bs[(wn4 + nt * 16 + lr) * 64 + ks * 32 + 8 * lg];
#pragma unroll
          for (int mt = 0; mt < 2; ++mt)
#pragma unroll
            for (int nt = 0; nt < 4; ++nt)
              acc[mt][nt] = __builtin_amdgcn_mfma_f32_16x16x32_f16(af[mt], bf[nt], acc[mt][nt], 0, 0, 0);
        }
        __syncthreads();
      }
      // epilogue: agent-coherent paired-dword stores
#pragma unroll
      for (int nt = 0; nt < 4; ++nt) {
        int n = n0 + wn4 + nt * 16 + lr;
        float bsum = b1i[n] + b1h[n];
#pragma unroll
        for (int mt = 0; mt < 2; ++mt) {
          int m = m0 + wm4 + mt * 16 + lg * 4;
#pragma unroll
          for (int r = 0; r < 4; ++r) {
            union { unsigned short us; f16 h; } cv;
            cv.h = (f16)(acc[mt][nt][r] + bsum);
            unsigned ov = (unsigned)__shfl_xor((int)(unsigned)cv.us, 1, 64);
            if (!(l & 1)) {
              unsigned pkv = ((unsigned)cv.us) | (ov << 16);
              __hip_atomic_store((unsigned*)(C + (size_t)(m + r) * 4096 + n), pkv,
                                 __ATOMIC_RELAXED, __HIP_MEMORY_SCOPE_AGENT);
            }
          }
        }
      }
      asm volatile("s_waitcnt vmcnt(0)" ::: "memory");
      __syncthreads();   // both groups drained (aligned barrier counts)
      if (tid == 0 || tid == 256)
        __hip_atomic_fetch_add(&gcnt[sj * 32 + mt_], 1u, __ATOMIC_RELAXED,
                               __HIP_MEMORY_SCOPE_AGENT);
    }
    return;
  }

  // ======================== scan roles ========================
  ScanSm* ss = (ScanSm*)smem;
  int role = (bi >= 256);            // 0: cell1, 1: cell2
  int idx = bi - (role ? 256 : 128);
  int s = idx >> 6, ut = idx & 63, u0 = ut * 16;
  const f16* G = s ? G0m : G0a;
  f16* H1s = H1h + (size_t)s * 64 * 32768;
  f16* H2o = HaHm + s * 1024;

  // weights -> registers, pinned; ALL indices static (rule #20)
  f16x8 wreg[8][4];
  if (role == 0) {
    const f16* Wp = s ? Wp1_m : Wp1_a;
#pragma unroll
    for (int ks = 0; ks < 4; ++ks)
#pragma unroll
      for (int g = 0; g < 4; ++g) {
        wreg[ks][g] = *(const f16x8*)(Wp + (size_t)((ut * 4 + g) * 32 + (w * 4 + ks)) * 512 + l * 8);
        asm volatile("" : "+v"(wreg[ks][g]));
      }
  } else {
    const f16* Wp = s ? Wp2_m : Wp2_a;
#pragma unroll
    for (int ks = 0; ks < 8; ++ks)
#pragma unroll
      for (int g = 0; g < 4; ++g) {
        wreg[ks][g] = *(const f16x8*)(Wp + (size_t)((ut * 4 + g) * 64 + (w * 8 + ks)) * 512 + l * 8);
        asm volatile("" : "+v"(wreg[ks][g]));
      }
  }

  // epilogue mapping: 1 cell per thread: (eb, u0+eu)
  int eb = tid >> 4, eu = tid & 15;
  int emt = eb >> 4, elg = (eb >> 2) & 3, er = eb & 3;
  int lred = elg * 16 + eu;
  int idxb = emt * 16 + er;
  float creg = 0.f;
  f32x4 zero = {0.f, 0.f, 0.f, 0.f};

  if (role == 0) {
    // ======================= cell 1: h1 chain =======================
    int pb = tid >> 4, pg2 = (tid >> 2) & 3, p4 = tid & 3;
    int cb = w * 128;
    for (int t = 0; t < 64; ++t) {
      // wait: G0 t-pair ready (32 n-tiles) and, for t>0, h1[t-1] flags
      if (w == 0) {
        waitcnt_ge(&gcnt[s * 32 + (t >> 1)], 32u);
        if (t > 0) waitflags(flags1 + (size_t)(s * 64 + t - 1) * 64, l);
      }
      __syncthreads();

      f16x4v gfrag = *(const f16x4v*)(G + (size_t)(t * 32 + pb) * 4096 + pg2 * 1024 + u0 + p4 * 4);

      f32x4 acc[2][4];
#pragma unroll
      for (int mt = 0; mt < 2; ++mt)
#pragma unroll
        for (int g = 0; g < 4; ++g) acc[mt][g] = zero;

      if (t > 0) {
        const f16* hp = H1s + (size_t)(t - 1) * 32768;
        f16x8 A0[4], A1[4];
#pragma unroll
        for (int ks = 0; ks < 4; ++ks) {
          int col = cb + ks * 32 + 8 * lg;
          A0[ks] = *(const f16x8*)(hp + lr * 1024 + col);
          A1[ks] = *(const f16x8*)(hp + (16 + lr) * 1024 + col);
        }
#pragma unroll
        for (int ks = 0; ks < 4; ++ks)
#pragma unroll
          for (int g = 0; g < 4; ++g) {
            acc[0][g] = __builtin_amdgcn_mfma_f32_16x16x32_f16(A0[ks], wreg[ks][g], acc[0][g], 0, 0, 0);
            acc[1][g] = __builtin_amdgcn_mfma_f32_16x16x32_f16(A1[ks], wreg[ks][g], acc[1][g], 0, 0, 0);
          }
      }

      *(f16x4v*)&ss->Gs[pb][pg2][p4 * 4] = gfrag;
#pragma unroll
      for (int mt = 0; mt < 2; ++mt)
#pragma unroll
        for (int g = 0; g < 4; ++g)
#pragma unroll
          for (int r = 0; r < 4; ++r)
            ss->red[w][l][(mt * 4 + g) * 4 + r] = acc[mt][g][r];
      __syncthreads();

      float pre[4];
#pragma unroll
      for (int g = 0; g < 4; ++g) {
        int idx2 = idxb + g * 4;
        pre[g] = ss->red[0][lred][idx2] + ss->red[1][lred][idx2] +
                 ss->red[2][lred][idx2] + ss->red[3][lred][idx2] +
                 ss->red[4][lred][idx2] + ss->red[5][lred][idx2] +
                 ss->red[6][lred][idx2] + ss->red[7][lred][idx2] +
                 (float)ss->Gs[eb][g][eu];
      }
      float cn = sigf(pre[1]) * creg + sigf(pre[0]) * tanh2(pre[2]);
      creg = cn;
      union { unsigned short us; f16 h; } cv;
      cv.h = (f16)(sigf(pre[3]) * tanh2(cn));
      unsigned ov = (unsigned)__shfl_xor((int)(unsigned)cv.us, 1, 64);
      if (!(tid & 1)) {
        unsigned pkv = ((unsigned)cv.us) | (ov << 16);
        __hip_atomic_store((unsigned*)(H1s + (size_t)t * 32768 + eb * 1024 + u0 + eu), pkv,
                           __ATOMIC_RELAXED, __HIP_MEMORY_SCOPE_AGENT);
      }
      asm volatile("s_waitcnt vmcnt(0)" ::: "memory");
      __syncthreads();   // block drained; red/Gs WAR
      if (tid == 0)
        __hip_atomic_store(flags1 + (size_t)(s * 64 + t) * 64 + ut, 1u,
                           __ATOMIC_RELAXED, __HIP_MEMORY_SCOPE_AGENT);
    }
  } else {
    // ======================= cell 2: h2 chain =======================
    const float* bip = s ? bi2_m : bi2_a;
    const float* bhp = s ? bh2_m : bh2_a;
    float b2r[4];
#pragma unroll
    for (int g = 0; g < 4; ++g)
      b2r[g] = bip[g * 1024 + u0 + eu] + bhp[g * 1024 + u0 + eu];
    int cb = (w & 3) * 256;

    for (int t = 0; t < 64; ++t) {
      f32x4 acc[2][4];
#pragma unroll
      for (int mt = 0; mt < 2; ++mt)
#pragma unroll
        for (int g = 0; g < 4; ++g) acc[mt][g] = zero;

      if (w == 0) waitflags(flags1 + (size_t)(s * 64 + t) * 64, l);
      if (t > 0 && w == 4) waitflags(flags2 + (size_t)(s * 64 + t - 1) * 64, l);
      __syncthreads();

      if (w < 4) {
        // Wih_2 half: consume h1[t]
        const f16* hp = H1s + (size_t)t * 32768;
        f16x8 A0[4], A1[4], B0[4], B1[4];
#pragma unroll
        for (int ks = 0; ks < 4; ++ks) {
          int c0 = cb + ks * 32 + 8 * lg;
          int c1 = cb + (4 + ks) * 32 + 8 * lg;
          A0[ks] = *(const f16x8*)(hp + lr * 1024 + c0);
          A1[ks] = *(const f16x8*)(hp + (16 + lr) * 1024 + c0);
          B0[ks] = *(const f16x8*)(hp + lr * 1024 + c1);
          B1[ks] = *(const f16x8*)(hp + (16 + lr) * 1024 + c1);
        }
#pragma unroll
        for (int ks = 0; ks < 4; ++ks)
#pragma unroll
          for (int g = 0; g < 4; ++g) {
            acc[0][g] = __builtin_amdgcn_mfma_f32_16x16x32_f16(A0[ks], wreg[ks][g], acc[0][g], 0, 0, 0);
            acc[1][g] = __builtin_amdgcn_mfma_f32_16x16x32_f16(A1[ks], wreg[ks][g], acc[1][g], 0, 0, 0);
          }
#pragma unroll
        for (int ks = 0; ks < 4; ++ks)
#pragma unroll
          for (int g = 0; g < 4; ++g) {
            acc[0][g] = __builtin_amdgcn_mfma_f32_16x16x32_f16(B0[ks], wreg[4 + ks][g], acc[0][g], 0, 0, 0);
            acc[1][g] = __builtin_amdgcn_mfma_f32_16x16x32_f16(B1[ks], wreg[4 + ks][g], acc[1][g], 0, 0, 0);
          }
      } else if (t > 0) {
        // Whh_2 half: consume h2[t-1] from t-major HaHm
        const f16* hp = HaHm + (size_t)((t - 1) * 32) * 2048 + s * 1024;
        f16x8 A0[4], A1[4], B0[4], B1[4];
#pragma unroll
        for (int ks = 0; ks < 4; ++ks) {
          int c0 = cb + ks * 32 + 8 * lg;
          int c1 = cb + (4 + ks) * 32 + 8 * lg;
          A0[ks] = *(const f16x8*)(hp + (size_t)lr * 2048 + c0);
          A1[ks] = *(const f16x8*)(hp + (size_t)(16 + lr) * 2048 + c0);
          B0[ks] = *(const f16x8*)(hp + (size_t)lr * 2048 + c1);
          B1[ks] = *(const f16x8*)(hp + (size_t)(16 + lr) * 2048 + c1);
        }
#pragma unroll
        for (int ks = 0; ks < 4; ++ks)
#pragma unroll
          for (int g = 0; g < 4; ++g) {
            acc[0][g] = __builtin_amdgcn_mfma_f32_16x16x32_f16(A0[ks], wreg[ks][g], acc[0][g], 0, 0, 0);
            acc[1][g] = __builtin_amdgcn_mfma_f32_16x16x32_f16(A1[ks], wreg[ks][g], acc[1][g], 0, 0, 0);
          }
#pragma unroll
        for (int ks = 0; ks < 4; ++ks)
#pragma unroll
          for (int g = 0; g < 4; ++g) {
            acc[0][g] = __builtin_amdgcn_mfma_f32_16x16x32_f16(B0[ks], wreg[4 + ks][g], acc[0][g], 0, 0, 0);
            acc[1][g] = __builtin_amdgcn_mfma_f32_16x16x32_f16(B1[ks], wreg[4 + ks][g], acc[1][g], 0, 0, 0);
          }
      }

#pragma unroll
      for (int mt = 0; mt < 2; ++mt)
#pragma unroll
        for (int g = 0; g < 4; ++g)
#pragma unroll
          for (int r = 0; r < 4; ++r)
            ss->red[w][l][(mt * 4 + g) * 4 + r] = acc[mt][g][r];
      __syncthreads();

      float pre[4];
#pragma unroll
      for (int g = 0; g < 4; ++g) {
        int idx2 = idxb + g * 4;
        pre[g] = ss->red[0][lred][idx2] + ss->red[1][lred][idx2] +
                 ss->red[2][lred][idx2] + ss->red[3][lred][idx2] +
                 ss->red[4][lred][idx2] + ss->red[5][lred][idx2] +
                 ss->red[6][lred][idx2] + ss->red[7][lred][idx2] + b2r[g];
      }
      float cn = sigf(pre[1]) * creg + sigf(pre[0]) * tanh2(pre[2]);
      creg = cn;
      union { unsigned short us; f16 h; } cv;
      cv.h = (f16)(sigf(pre[3]) * tanh2(cn));
      unsigned ov = (unsigned)__shfl_xor((int)(unsigned)cv.us, 1, 64);
      if (!(tid & 1)) {
        unsigned pkv = ((unsigned)cv.us) | (ov << 16);
        __hip_atomic_store((unsigned*)(H2o + (size_t)(t * 32 + eb) * 2048 + u0 + eu), pkv,
                           __ATOMIC_RELAXED, __HIP_MEMORY_SCOPE_AGENT);
      }
      asm volatile("s_waitcnt vmcnt(0)" ::: "memory");
      __syncthreads();   // block drained; red WAR
      if (tid == 0)
        __hip_atomic_store(flags2 + (size_t)(s * 64 + t) * 64 + ut, 1u,
                           __ATOMIC_RELAXED, __HIP_MEMORY_SCOPE_AGENT);
    }
  }
}

// ---------------- fusion ----------------------------------------------------
DEV void gemm_phase(const f16* __restrict__ H, int kA0,
                    const f16* __restrict__ Bp, int brs, int nk,
                    f16* As, f16* Bs, int m0, int n0, int w, int l,
                    int wm, int wn, f32x4 (&acc)[4][2]) {
  f32x4 zero = {0.f, 0.f, 0.f, 0.f};
#pragma unroll
  for (int mt = 0; mt < 4; ++mt)
#pragma unroll
    for (int nt = 0; nt < 2; ++nt) acc[mt][nt] = zero;
  int lr = l & 15, lg = l >> 4;
  int sc = (l & 7) * 8;
  for (int kt = 0; kt < nk; ++kt) {
    int ka = kA0 + kt * 64, kb = kt * 64;
#pragma unroll
    for (int c2 = 0; c2 < 4; ++c2)
      GLDS16(H + (size_t)(m0 + w * 32 + c2 * 8 + (l >> 3)) * 2048 + ka + sc,
             As + (w * 32 + c2 * 8) * 64);
#pragma unroll
    for (int c2 = 0; c2 < 2; ++c2)
      GLDS16(Bp + (size_t)(n0 + w * 16 + c2 * 8 + (l >> 3)) * brs + kb + sc,
             Bs + (w * 16 + c2 * 8) * 64);
    __syncthreads();
#pragma unroll
    for (int ks = 0; ks < 2; ++ks) {
      f16x8 af[4], bf[2];
#pragma unroll
      for (int mt = 0; mt < 4; ++mt)
        af[mt] = *(const f16x8*)&As[(wm + mt * 16 + lr) * 64 + ks * 32 + 8 * lg];
#pragma unroll
      for (int nt = 0; nt < 2; ++nt)
        bf[nt] = *(const f16x8*)&Bs[(wn + nt * 16 + lr) * 64 + ks * 32 + 8 * lg];
#pragma unroll
      for (int mt = 0; mt < 4; ++mt)
#pragma unroll
        for (int nt = 0; nt < 2; ++nt)
          acc[mt][nt] = __builtin_amdgcn_mfma_f32_16x16x32_f16(af[mt], bf[nt], acc[mt][nt], 0, 0, 0);
    }
    __syncthreads();
  }
}

__global__ __launch_bounds__(256) void k_fusion(
    const f16* __restrict__ H, const f16* __restrict__ Wg16,
    const f16* __restrict__ Wa16, const f16* __restrict__ Wm16,
    const float* __restrict__ bg, const float* __restrict__ ba,
    const float* __restrict__ bm, float* __restrict__ out) {
  __shared__ alignas(16) f16 As[128 * 64];
  __shared__ alignas(16) f16 Bs[64 * 64];
  int tid = threadIdx.x, l = tid & 63, w = tid >> 6;
  int m0 = blockIdx.x * 128, n0 = blockIdx.y * 64;
  int wm = (w & 1) * 64, wn = (w >> 1) * 32;
  int lr = l & 15, lg = l >> 4;

  f32x4 acc[4][2];
  float ta[4][2][4], tm[4][2][4];

  gemm_phase(H, 0, Wa16, 1024, 16, As, Bs, m0, n0, w, l, wm, wn, acc);
#pragma unroll
  for (int nt = 0; nt < 2; ++nt) {
    float bv = ba[n0 + wn + nt * 16 + lr];
#pragma unroll
    for (int mt = 0; mt < 4; ++mt)
#pragma unroll
      for (int r = 0; r < 4; ++r) ta[mt][nt][r] = tanh2(acc[mt][nt][r] + bv);
  }
  gemm_phase(H, 1024, Wm16, 1024, 16, As, Bs, m0, n0, w, l, wm, wn, acc);
#pragma unroll
  for (int nt = 0; nt < 2; ++nt) {
    float bv = bm[n0 + wn + nt * 16 + lr];
#pragma unroll
    for (int mt = 0; mt < 4; ++mt)
#pragma unroll
      for (int r = 0; r < 4; ++r) tm[mt][nt][r] = tanh2(acc[mt][nt][r] + bv);
  }
  gemm_phase(H, 0, Wg16, 2048, 32, As, Bs, m0, n0, w, l, wm, wn, acc);
#pragma unroll
  for (int nt = 0; nt < 2; ++nt) {
    int n = n0 + wn + nt * 16 + lr;
    float bv = bg[n];
#pragma unroll
    for (int mt = 0; mt < 4; ++mt) {
      int m = m0 + wm + mt * 16 + lg * 4;
#pragma unroll
      for (int r = 0; r < 4; ++r) {
        float g = sigf(acc[mt][nt][r] + bv);
        int mr = m + r;                       // row t*32+b
        size_t orow = (size_t)((mr & 31) * 64 + (mr >> 5));   // b*64+t
        out[orow * 1024 + n] = tm[mt][nt][r] + g * (ta[mt][nt][r] - tm[mt][nt][r]);
      }
    }
  }
}

// ===========================================================================
extern "C" void kernel_launch(void* const* d_in, const int* in_sizes, int n_in,
                              void* d_out, int out_size, void* d_ws, size_t ws_size,
                              hipStream_t stream) {
  const float* xa = (const float*)d_in[0];
  const float* xm = (const float*)d_in[1];
  const float* Wih_1a = (const float*)d_in[2];
  const float* Whh_1a = (const float*)d_in[3];
  const float* bih_1a = (const float*)d_in[4];
  const float* bhh_1a = (const float*)d_in[5];
  const float* Wih_2a = (const float*)d_in[6];
  const float* Whh_2a = (const float*)d_in[7];
  const float* bih_2a = (const float*)d_in[8];
  const float* bhh_2a = (const float*)d_in[9];
  const float* Wih_1m = (const float*)d_in[10];
  const float* Whh_1m = (const float*)d_in[11];
  const float* bih_1m = (const float*)d_in[12];
  const float* bhh_1m = (const float*)d_in[13];
  const float* Wih_2m = (const float*)d_in[14];
  const float* Whh_2m = (const float*)d_in[15];
  const float* bih_2m = (const float*)d_in[16];
  const float* bhh_2m = (const float*)d_in[17];
  const float* Wg = (const float*)d_in[18];
  const float* bg = (const float*)d_in[19];
  const float* Wa = (const float*)d_in[20];
  const float* ba = (const float*)d_in[21];
  const float* Wm = (const float*)d_in[22];
  const float* bm = (const float*)d_in[23];

  char* ws = (char*)d_ws;
  const size_t MB = 1024ull * 1024;
  if (ws_size < 138 * MB) return;  // fail visibly

  f16* xt_a  = (f16*)(ws + 0 * MB);    // [t*32+b][2048]
  f16* xt_m  = (f16*)(ws + 8 * MB);
  f16* W1p_a = (f16*)(ws + 16 * MB);
  f16* W1p_m = (f16*)(ws + 24 * MB);
  f16* W2p_a = (f16*)(ws + 32 * MB);
  f16* W2p_m = (f16*)(ws + 48 * MB);
  f16* Wg16  = (f16*)(ws + 64 * MB);
  f16* Wa16  = (f16*)(ws + 68 * MB);
  f16* Wm16  = (f16*)(ws + 70 * MB);
  f16* G0a   = (f16*)(ws + 72 * MB);   // [t*32+b][4096]
  f16* G0m   = (f16*)(ws + 88 * MB);
  f16* H1h   = (f16*)(ws + 104 * MB);  // 8 MB
  f16* HaHm  = (f16*)(ws + 112 * MB);  // 8 MB, [t*32+b][2048]
  unsigned* flags1 = (unsigned*)(ws + 120 * MB);
  unsigned* flags2 = (unsigned*)(ws + 120 * MB + 32768);
  unsigned* gcnt   = (unsigned*)(ws + 120 * MB + 65536);

  dim3 B256(256);
  k_cvt_all<<<12288, B256, 0, stream>>>(xa, xt_a, xm, xt_m, Wg, Wg16, Wa, Wa16,
                                        Wm, Wm16);
  k_packw1<<<dim3(2048, 2), B256, 0, stream>>>(Whh_1a, Whh_1m, W1p_a, W1p_m);
  k_packw2<<<dim3(4096, 2), B256, 0, stream>>>(Wih_2a, Whh_2a, Wih_2m, Whh_2m,
                                               W2p_a, W2p_m);
  hipMemsetAsync(flags1, 0, 131072, stream);   // flags1 + flags2 + gcnt

  // fused dataflow: G0-GEMM producers + cell1 + cell2
  k_scan2<<<384, dim3(512), 0, stream>>>(
      W1p_a, W1p_m, W2p_a, W2p_m, xt_a, xt_m, Wih_1a, Wih_1m,
      bih_1a, bhh_1a, bih_1m, bhh_1m,
      bih_2a, bhh_2a, bih_2m, bhh_2m,
      G0a, G0m, H1h, HaHm, flags1, flags2, gcnt);

  k_fusion<<<dim3(16, 16), B256, 0, stream>>>(HaHm, Wg16, Wa16, Wm16, bg, ba,
                                              bm, (float*)d_out);
}

// Round 16
// 725.295 us; speedup vs baseline: 1.9968x; 1.9968x over previous
//
#include <hip/hip_runtime.h>
#include <cstdint>

typedef _Float16 f16;
typedef _Float16 f16x4v __attribute__((ext_vector_type(4)));
typedef _Float16 f16x8 __attribute__((ext_vector_type(8)));
typedef float f32x4 __attribute__((ext_vector_type(4)));

#define DEV static __device__ __forceinline__

// async global->LDS, 16B per lane; LDS dest = wave-uniform base + lane*16
#define GLDS16(gp, lp) __builtin_amdgcn_global_load_lds( \
    (const __attribute__((address_space(1))) void*)(gp), \
    (__attribute__((address_space(3))) void*)(lp), 16, 0, 0)

DEV float sigf(float x) { return 1.0f / (1.0f + __expf(-x)); }
DEV float tanh2(float x) {
  float e = __expf(-2.0f * fabsf(x));
  float t = (1.0f - e) / (1.0f + e);
  return x >= 0.0f ? t : -t;
}

// this wave polls N contiguous producer flags (1 dword per lane, agent-scope)
template <int N>
DEV void waitflagsN(const unsigned* fp, int l) {
  unsigned f;
  do {
    f = (l < N) ? __hip_atomic_load(fp + l, __ATOMIC_RELAXED,
                                    __HIP_MEMORY_SCOPE_AGENT) : 1u;
  } while (__any(f == 0));
  asm volatile("" ::: "memory");
  __builtin_amdgcn_sched_barrier(0);
}

// ---------------- merged fp32 -> fp16 convert (7 segments) ----------------
__global__ __launch_bounds__(256) void k_cvt_all(
    const float* __restrict__ s0, f16* __restrict__ d0,
    const float* __restrict__ s1, f16* __restrict__ d1,
    const float* __restrict__ s2, f16* __restrict__ d2,
    const float* __restrict__ s3, f16* __restrict__ d3,
    const float* __restrict__ s4, f16* __restrict__ d4,
    const float* __restrict__ s5, f16* __restrict__ d5,
    const float* __restrict__ s6, f16* __restrict__ d6) {
  int bid = blockIdx.x;
  const float* s; f16* d; int base;
  if (bid < 4096)       { s = s0; d = d0; base = bid; }
  else if (bid < 8192)  { s = s1; d = d1; base = bid - 4096; }
  else if (bid < 16384) { s = s2; d = d2; base = bid - 8192; }
  else if (bid < 24576) { s = s3; d = d3; base = bid - 16384; }
  else if (bid < 26624) { s = s4; d = d4; base = bid - 24576; }
  else if (bid < 27648) { s = s5; d = d5; base = bid - 26624; }
  else                  { s = s6; d = d6; base = bid - 27648; }
  int i = (base * 256 + threadIdx.x) * 4;
  float4 v = *(const float4*)(s + i);
  f16x4v o;
  o.x = (f16)v.x; o.y = (f16)v.y; o.z = (f16)v.z; o.w = (f16)v.w;
  *(f16x4v*)(d + i) = o;
}

// ---------------- pack Whh (4096x1024 fp32), K=1024 (kt 0..31) -------------
__global__ __launch_bounds__(256) void k_packw1(const float* __restrict__ Wa,
                                                const float* __restrict__ Wm,
                                                f16* __restrict__ Pa,
                                                f16* __restrict__ Pm) {
  const float* W = blockIdx.y ? Wm : Wa;
  f16* P = blockIdx.y ? Pm : Pa;
  int i2 = blockIdx.x * 256 + threadIdx.x;
  int l = i2 & 63, frag = i2 >> 6;
  int kt = frag & 31, ug = frag >> 5;
  int gate = ug & 3, ut = ug >> 2;
  int row = gate * 1024 + ut * 16 + (l & 15);
  int k = kt * 32 + 8 * (l >> 4);
  const float* s = W + row * 1024 + k;
  f16x8 o;
#pragma unroll
  for (int j = 0; j < 8; ++j) o[j] = (f16)s[j];
  *(f16x8*)(P + frag * 512 + l * 8) = o;
}

// ---------------- pack [Wih_2 | Whh_2] as K=2048 (kt 0..63) ----------------
__global__ __launch_bounds__(256) void k_packw2(const float* __restrict__ Wiha,
                                                const float* __restrict__ Whha,
                                                const float* __restrict__ Wihm,
                                                const float* __restrict__ Whhm,
                                                f16* __restrict__ Pa,
                                                f16* __restrict__ Pm) {
  const float* Wih = blockIdx.y ? Wihm : Wiha;
  const float* Whh = blockIdx.y ? Whhm : Whha;
  f16* P = blockIdx.y ? Pm : Pa;
  int i2 = blockIdx.x * 256 + threadIdx.x;
  int l = i2 & 63, frag = i2 >> 6;
  int kt = frag & 63, ug = frag >> 6;
  int gate = ug & 3, ut = ug >> 2;
  int row = gate * 1024 + ut * 16 + (l & 15);
  int k = kt * 32 + 8 * (l >> 4);
  const float* s = (k < 1024) ? (Wih + row * 1024 + k)
                              : (Whh + row * 1024 + (k - 1024));
  f16x8 o;
#pragma unroll
  for (int j = 0; j < 8; ++j) o[j] = (f16)s[j];
  *(f16x8*)(P + frag * 512 + l * 8) = o;
}

// ---------------- big GEMM: C = A @ B^T + (bi+bh), fp16 out ----------------
template <int NKT, int LDA>
__global__ __launch_bounds__(256) void k_igemm(
    const f16* __restrict__ A0, const f16* __restrict__ A1,
    const f16* __restrict__ B0, const f16* __restrict__ B1,
    const float* __restrict__ bi0, const float* __restrict__ bh0,
    const float* __restrict__ bi1, const float* __restrict__ bh1,
    f16* __restrict__ C0, f16* __restrict__ C1) {
  const f16* A = blockIdx.z ? A1 : A0;
  const f16* B = blockIdx.z ? B1 : B0;
  const float* bi = blockIdx.z ? bi1 : bi0;
  const float* bh = blockIdx.z ? bh1 : bh0;
  f16* C = blockIdx.z ? C1 : C0;

  __shared__ alignas(16) f16 As[128 * 64];
  __shared__ alignas(16) f16 Bs[128 * 64];

  int tid = threadIdx.x, l = tid & 63, w = tid >> 6;
  int m0 = blockIdx.x * 128, n0 = blockIdx.y * 128;
  int wm = (w & 1) * 64, wn = (w >> 1) * 64;
  int lr = l & 15, lg = l >> 4;
  int sr = w * 32 + (l >> 3);
  int sc = (l & 7) * 8;

  f32x4 acc[4][4];
  f32x4 zero = {0.f, 0.f, 0.f, 0.f};
#pragma unroll
  for (int mt = 0; mt < 4; ++mt)
#pragma unroll
    for (int nt = 0; nt < 4; ++nt) acc[mt][nt] = zero;

  for (int kt = 0; kt < NKT; ++kt) {
    int k0 = kt * 64;
#pragma unroll
    for (int c2 = 0; c2 < 4; ++c2) {
      GLDS16(A + (size_t)(m0 + sr + c2 * 8) * LDA + k0 + sc, &As[(w * 32 + c2 * 8) * 64]);
      GLDS16(B + (size_t)(n0 + sr + c2 * 8) * LDA + k0 + sc, &Bs[(w * 32 + c2 * 8) * 64]);
    }
    __syncthreads();
#pragma unroll
    for (int ks = 0; ks < 2; ++ks) {
      f16x8 af[4], bf[4];
#pragma unroll
      for (int mt = 0; mt < 4; ++mt)
        af[mt] = *(const f16x8*)&As[(wm + mt * 16 + lr) * 64 + ks * 32 + 8 * lg];
#pragma unroll
      for (int nt = 0; nt < 4; ++nt)
        bf[nt] = *(const f16x8*)&Bs[(wn + nt * 16 + lr) * 64 + ks * 32 + 8 * lg];
#pragma unroll
      for (int mt = 0; mt < 4; ++mt)
#pragma unroll
        for (int nt = 0; nt < 4; ++nt)
          acc[mt][nt] = __builtin_amdgcn_mfma_f32_16x16x32_f16(af[mt], bf[nt], acc[mt][nt], 0, 0, 0);
    }
    __syncthreads();
  }

#pragma unroll
  for (int nt = 0; nt < 4; ++nt) {
    int n = n0 + wn + nt * 16 + lr;
    float bsum = bi[n] + bh[n];
#pragma unroll
    for (int mt = 0; mt < 4; ++mt) {
      int m = m0 + wm + mt * 16 + lg * 4;
#pragma unroll
      for (int r = 0; r < 4; ++r)
        C[(size_t)(m + r) * 4096 + n] = (f16)(acc[mt][nt][r] + bsum);
    }
  }
}

// ---------------- dataflow scan: per-wave polling, 2 barriers/step ----------
// R14 base with ONE change: each wave polls only ITS producers' flags (8 for
// cell1, 16 for cell2) and proceeds directly to its loads — no post-poll
// block barrier. Producer skew is absorbed per-wave; syncB/syncC unchanged.
// WAR safe: a wave re-writes red/Gs at t+1 only after syncC(t), which orders
// it after every wave's epilogue reads at t.
__global__ __launch_bounds__(512, 1) void k_scan2(
    const f16* __restrict__ Wp1_a, const f16* __restrict__ Wp1_m,
    const f16* __restrict__ Wp2_a, const f16* __restrict__ Wp2_m,
    const f16* __restrict__ G_a, const f16* __restrict__ G_m,
    const float* __restrict__ bi2_a, const float* __restrict__ bh2_a,
    const float* __restrict__ bi2_m, const float* __restrict__ bh2_m,
    f16* __restrict__ H1h,            // [s][t][b][u] 2x64x32x1024
    f16* __restrict__ h2c,            // [s][t][b][u] 2x64x32x1024 (compact h2)
    f16* __restrict__ HaHm,           // [(b*64+t)*2048 + s*1024 + u]
    unsigned* __restrict__ flags1,    // [s][t][64] dwords, zeroed
    unsigned* __restrict__ flags2) {  // [s][t][64] dwords, zeroed
  int bi = blockIdx.x;
  int role = bi >> 7, s = (bi >> 6) & 1, ut = bi & 63, u0 = ut * 16;
  int tid = threadIdx.x, l = tid & 63, w = tid >> 6;   // w in [0,8)
  int lr = l & 15, lg = l >> 4;
  const f16* G = s ? G_m : G_a;
  f16* H1s = H1h + (size_t)s * 64 * 32768;
  f16* h2s = h2c + (size_t)s * 64 * 32768;
  f16* H2o = HaHm + s * 1024;

  // weights -> registers, pinned; ALL indices static (rule #20)
  f16x8 wreg[8][4];
  if (role == 0) {
    const f16* Wp = s ? Wp1_m : Wp1_a;
#pragma unroll
    for (int ks = 0; ks < 4; ++ks)
#pragma unroll
      for (int g = 0; g < 4; ++g) {
        wreg[ks][g] = *(const f16x8*)(Wp + (size_t)((ut * 4 + g) * 32 + (w * 4 + ks)) * 512 + l * 8);
        asm volatile("" : "+v"(wreg[ks][g]));
      }
  } else {
    const f16* Wp = s ? Wp2_m : Wp2_a;
#pragma unroll
    for (int ks = 0; ks < 8; ++ks)
#pragma unroll
      for (int g = 0; g < 4; ++g) {
        wreg[ks][g] = *(const f16x8*)(Wp + (size_t)((ut * 4 + g) * 64 + (w * 8 + ks)) * 512 + l * 8);
        asm volatile("" : "+v"(wreg[ks][g]));
      }
  }

  __shared__ alignas(16) float red[8][64][33];
  __shared__ alignas(16) f16 Gs[32][4][16];

  // epilogue mapping: 1 cell per thread: (eb, u0+eu)
  int eb = tid >> 4, eu = tid & 15;
  int emt = eb >> 4, elg = (eb >> 2) & 3, er = eb & 3;
  int lred = elg * 16 + eu;
  int idxb = emt * 16 + er;
  float creg = 0.f;
  f32x4 zero = {0.f, 0.f, 0.f, 0.f};

  if (role == 0) {
    // ======================= cell 1: h1 chain =======================
    int pb = tid >> 4, pg2 = (tid >> 2) & 3, p4 = tid & 3;
    int cb = w * 128;
    for (int t = 0; t < 64; ++t) {
      f16x4v gfrag = *(const f16x4v*)(G + (size_t)(pb * 64 + t) * 4096 + pg2 * 1024 + u0 + p4 * 4);

      f32x4 acc[2][4];
#pragma unroll
      for (int mt = 0; mt < 2; ++mt)
#pragma unroll
        for (int g = 0; g < 4; ++g) acc[mt][g] = zero;

      if (t > 0) {
        // this wave needs producers 8w..8w+7 of step t-1 (cols cb..cb+127)
        waitflagsN<8>(flags1 + (size_t)(s * 64 + t - 1) * 64 + 8 * w, l);
        const f16* hp = H1s + (size_t)(t - 1) * 32768;
        f16x8 A0[4], A1[4];
#pragma unroll
        for (int ks = 0; ks < 4; ++ks) {
          int col = cb + ks * 32 + 8 * lg;
          A0[ks] = *(const f16x8*)(hp + lr * 1024 + col);
          A1[ks] = *(const f16x8*)(hp + (16 + lr) * 1024 + col);
        }
#pragma unroll
        for (int ks = 0; ks < 4; ++ks)
#pragma unroll
          for (int g = 0; g < 4; ++g) {
            acc[0][g] = __builtin_amdgcn_mfma_f32_16x16x32_f16(A0[ks], wreg[ks][g], acc[0][g], 0, 0, 0);
            acc[1][g] = __builtin_amdgcn_mfma_f32_16x16x32_f16(A1[ks], wreg[ks][g], acc[1][g], 0, 0, 0);
          }
      }

      *(f16x4v*)&Gs[pb][pg2][p4 * 4] = gfrag;
#pragma unroll
      for (int mt = 0; mt < 2; ++mt)
#pragma unroll
        for (int g = 0; g < 4; ++g)
#pragma unroll
          for (int r = 0; r < 4; ++r)
            red[w][l][(mt * 4 + g) * 4 + r] = acc[mt][g][r];
      __syncthreads();   // barrier B

      float pre[4];
#pragma unroll
      for (int g = 0; g < 4; ++g) {
        int idx = idxb + g * 4;
        pre[g] = red[0][lred][idx] + red[1][lred][idx] + red[2][lred][idx] +
                 red[3][lred][idx] + red[4][lred][idx] + red[5][lred][idx] +
                 red[6][lred][idx] + red[7][lred][idx] + (float)Gs[eb][g][eu];
      }
      float cn = sigf(pre[1]) * creg + sigf(pre[0]) * tanh2(pre[2]);
      creg = cn;
      union { unsigned short us; f16 h; } cv;
      cv.h = (f16)(sigf(pre[3]) * tanh2(cn));
      unsigned ov = (unsigned)__shfl_xor((int)(unsigned)cv.us, 1, 64);
      if (!(tid & 1)) {
        unsigned pkv = ((unsigned)cv.us) | (ov << 16);
        __hip_atomic_store((unsigned*)(H1s + (size_t)t * 32768 + eb * 1024 + u0 + eu), pkv,
                           __ATOMIC_RELAXED, __HIP_MEMORY_SCOPE_AGENT);
      }
      asm volatile("s_waitcnt vmcnt(0)" ::: "memory");
      __syncthreads();   // barrier C: block drained; red/Gs WAR
      if (tid == 0)
        __hip_atomic_store(flags1 + (size_t)(s * 64 + t) * 64 + ut, 1u,
                           __ATOMIC_RELAXED, __HIP_MEMORY_SCOPE_AGENT);
    }
  } else {
    // ======================= cell 2: h2 chain =======================
    const float* bip = s ? bi2_m : bi2_a;
    const float* bhp = s ? bh2_m : bh2_a;
    float b2r[4];
#pragma unroll
    for (int g = 0; g < 4; ++g)
      b2r[g] = bip[g * 1024 + u0 + eu] + bhp[g * 1024 + u0 + eu];
    int cb = (w & 3) * 256;

    for (int t = 0; t < 64; ++t) {
      f32x4 acc[2][4];
#pragma unroll
      for (int mt = 0; mt < 2; ++mt)
#pragma unroll
        for (int g = 0; g < 4; ++g) acc[mt][g] = zero;

      if (w < 4) {
        // Wih_2 half: consume h1[t] (producers 16(w&3)..+15)
        waitflagsN<16>(flags1 + (size_t)(s * 64 + t) * 64 + 16 * (w & 3), l);
        const f16* hp = H1s + (size_t)t * 32768;
        f16x8 A0[4], A1[4], B0[4], B1[4];
#pragma unroll
        for (int ks = 0; ks < 4; ++ks) {
          int c0 = cb + ks * 32 + 8 * lg;
          int c1 = cb + (4 + ks) * 32 + 8 * lg;
          A0[ks] = *(const f16x8*)(hp + lr * 1024 + c0);
          A1[ks] = *(const f16x8*)(hp + (16 + lr) * 1024 + c0);
          B0[ks] = *(const f16x8*)(hp + lr * 1024 + c1);
          B1[ks] = *(const f16x8*)(hp + (16 + lr) * 1024 + c1);
        }
#pragma unroll
        for (int ks = 0; ks < 4; ++ks)
#pragma unroll
          for (int g = 0; g < 4; ++g) {
            acc[0][g] = __builtin_amdgcn_mfma_f32_16x16x32_f16(A0[ks], wreg[ks][g], acc[0][g], 0, 0, 0);
            acc[1][g] = __builtin_amdgcn_mfma_f32_16x16x32_f16(A1[ks], wreg[ks][g], acc[1][g], 0, 0, 0);
          }
#pragma unroll
        for (int ks = 0; ks < 4; ++ks)
#pragma unroll
          for (int g = 0; g < 4; ++g) {
            acc[0][g] = __builtin_amdgcn_mfma_f32_16x16x32_f16(B0[ks], wreg[4 + ks][g], acc[0][g], 0, 0, 0);
            acc[1][g] = __builtin_amdgcn_mfma_f32_16x16x32_f16(B1[ks], wreg[4 + ks][g], acc[1][g], 0, 0, 0);
          }
      } else if (t > 0) {
        // Whh_2 half: consume h2[t-1] (producers 16(w&3)..+15)
        waitflagsN<16>(flags2 + (size_t)(s * 64 + t - 1) * 64 + 16 * (w & 3), l);
        const f16* hp = h2s + (size_t)(t - 1) * 32768;
        f16x8 A0[4], A1[4], B0[4], B1[4];
#pragma unroll
        for (int ks = 0; ks < 4; ++ks) {
          int c0 = cb + ks * 32 + 8 * lg;
          int c1 = cb + (4 + ks) * 32 + 8 * lg;
          A0[ks] = *(const f16x8*)(hp + lr * 1024 + c0);
          A1[ks] = *(const f16x8*)(hp + (16 + lr) * 1024 + c0);
          B0[ks] = *(const f16x8*)(hp + lr * 1024 + c1);
          B1[ks] = *(const f16x8*)(hp + (16 + lr) * 1024 + c1);
        }
#pragma unroll
        for (int ks = 0; ks < 4; ++ks)
#pragma unroll
          for (int g = 0; g < 4; ++g) {
            acc[0][g] = __builtin_amdgcn_mfma_f32_16x16x32_f16(A0[ks], wreg[ks][g], acc[0][g], 0, 0, 0);
            acc[1][g] = __builtin_amdgcn_mfma_f32_16x16x32_f16(A1[ks], wreg[ks][g], acc[1][g], 0, 0, 0);
          }
#pragma unroll
        for (int ks = 0; ks < 4; ++ks)
#pragma unroll
          for (int g = 0; g < 4; ++g) {
            acc[0][g] = __builtin_amdgcn_mfma_f32_16x16x32_f16(B0[ks], wreg[4 + ks][g], acc[0][g], 0, 0, 0);
            acc[1][g] = __builtin_amdgcn_mfma_f32_16x16x32_f16(B1[ks], wreg[4 + ks][g], acc[1][g], 0, 0, 0);
          }
      }

#pragma unroll
      for (int mt = 0; mt < 2; ++mt)
#pragma unroll
        for (int g = 0; g < 4; ++g)
#pragma unroll
          for (int r = 0; r < 4; ++r)
            red[w][l][(mt * 4 + g) * 4 + r] = acc[mt][g][r];
      __syncthreads();   // barrier B

      float pre[4];
#pragma unroll
      for (int g = 0; g < 4; ++g) {
        int idx = idxb + g * 4;
        pre[g] = red[0][lred][idx] + red[1][lred][idx] + red[2][lred][idx] +
                 red[3][lred][idx] + red[4][lred][idx] + red[5][lred][idx] +
                 red[6][lred][idx] + red[7][lred][idx] + b2r[g];
      }
      float cn = sigf(pre[1]) * creg + sigf(pre[0]) * tanh2(pre[2]);
      creg = cn;
      union { unsigned short us; f16 h; } cv;
      cv.h = (f16)(sigf(pre[3]) * tanh2(cn));
      unsigned ov = (unsigned)__shfl_xor((int)(unsigned)cv.us, 1, 64);
      if (!(tid & 1)) {
        unsigned pkv = ((unsigned)cv.us) | (ov << 16);
        __hip_atomic_store((unsigned*)(h2s + (size_t)t * 32768 + eb * 1024 + u0 + eu), pkv,
                           __ATOMIC_RELAXED, __HIP_MEMORY_SCOPE_AGENT);
        *(unsigned*)(H2o + (size_t)(eb * 64 + t) * 2048 + u0 + eu) = pkv;
      }
      asm volatile("s_waitcnt vmcnt(0)" ::: "memory");
      __syncthreads();   // barrier C: block drained; red WAR
      if (tid == 0)
        __hip_atomic_store(flags2 + (size_t)(s * 64 + t) * 64 + ut, 1u,
                           __ATOMIC_RELAXED, __HIP_MEMORY_SCOPE_AGENT);
    }
  }
}

// ---------------- fusion ----------------------------------------------------
DEV void gemm_phase(const f16* __restrict__ H, int kA0,
                    const f16* __restrict__ Bp, int brs, int nk,
                    f16* As, f16* Bs, int m0, int n0, int w, int l,
                    int wm, int wn, f32x4 (&acc)[4][2]) {
  f32x4 zero = {0.f, 0.f, 0.f, 0.f};
#pragma unroll
  for (int mt = 0; mt < 4; ++mt)
#pragma unroll
    for (int nt = 0; nt < 2; ++nt) acc[mt][nt] = zero;
  int lr = l & 15, lg = l >> 4;
  int sc = (l & 7) * 8;
  for (int kt = 0; kt < nk; ++kt) {
    int ka = kA0 + kt * 64, kb = kt * 64;
#pragma unroll
    for (int c2 = 0; c2 < 4; ++c2)
      GLDS16(H + (size_t)(m0 + w * 32 + c2 * 8 + (l >> 3)) * 2048 + ka + sc,
             As + (w * 32 + c2 * 8) * 64);
#pragma unroll
    for (int c2 = 0; c2 < 2; ++c2)
      GLDS16(Bp + (size_t)(n0 + w * 16 + c2 * 8 + (l >> 3)) * brs + kb + sc,
             Bs + (w * 16 + c2 * 8) * 64);
    __syncthreads();
#pragma unroll
    for (int ks = 0; ks < 2; ++ks) {
      f16x8 af[4], bf[2];
#pragma unroll
      for (int mt = 0; mt < 4; ++mt)
        af[mt] = *(const f16x8*)&As[(wm + mt * 16 + lr) * 64 + ks * 32 + 8 * lg];
#pragma unroll
      for (int nt = 0; nt < 2; ++nt)
        bf[nt] = *(const f16x8*)&Bs[(wn + nt * 16 + lr) * 64 + ks * 32 + 8 * lg];
#pragma unroll
      for (int mt = 0; mt < 4; ++mt)
#pragma unroll
        for (int nt = 0; nt < 2; ++nt)
          acc[mt][nt] = __builtin_amdgcn_mfma_f32_16x16x32_f16(af[mt], bf[nt], acc[mt][nt], 0, 0, 0);
    }
    __syncthreads();
  }
}

__global__ __launch_bounds__(256) void k_fusion(
    const f16* __restrict__ H, const f16* __restrict__ Wg16,
    const f16* __restrict__ Wa16, const f16* __restrict__ Wm16,
    const float* __restrict__ bg, const float* __restrict__ ba,
    const float* __restrict__ bm, float* __restrict__ out) {
  __shared__ alignas(16) f16 As[128 * 64];
  __shared__ alignas(16) f16 Bs[64 * 64];
  int tid = threadIdx.x, l = tid & 63, w = tid >> 6;
  int m0 = blockIdx.x * 128, n0 = blockIdx.y * 64;
  int wm = (w & 1) * 64, wn = (w >> 1) * 32;
  int lr = l & 15, lg = l >> 4;

  f32x4 acc[4][2];
  float ta[4][2][4], tm[4][2][4];

  gemm_phase(H, 0, Wa16, 1024, 16, As, Bs, m0, n0, w, l, wm, wn, acc);
#pragma unroll
  for (int nt = 0; nt < 2; ++nt) {
    float bv = ba[n0 + wn + nt * 16 + lr];
#pragma unroll
    for (int mt = 0; mt < 4; ++mt)
#pragma unroll
      for (int r = 0; r < 4; ++r) ta[mt][nt][r] = tanh2(acc[mt][nt][r] + bv);
  }
  gemm_phase(H, 1024, Wm16, 1024, 16, As, Bs, m0, n0, w, l, wm, wn, acc);
#pragma unroll
  for (int nt = 0; nt < 2; ++nt) {
    float bv = bm[n0 + wn + nt * 16 + lr];
#pragma unroll
    for (int mt = 0; mt < 4; ++mt)
#pragma unroll
      for (int r = 0; r < 4; ++r) tm[mt][nt][r] = tanh2(acc[mt][nt][r] + bv);
  }
  gemm_phase(H, 0, Wg16, 2048, 32, As, Bs, m0, n0, w, l, wm, wn, acc);
#pragma unroll
  for (int nt = 0; nt < 2; ++nt) {
    int n = n0 + wn + nt * 16 + lr;
    float bv = bg[n];
#pragma unroll
    for (int mt = 0; mt < 4; ++mt) {
      int m = m0 + wm + mt * 16 + lg * 4;
#pragma unroll
      for (int r = 0; r < 4; ++r) {
        float g = sigf(acc[mt][nt][r] + bv);
        out[(size_t)(m + r) * 1024 + n] = tm[mt][nt][r] + g * (ta[mt][nt][r] - tm[mt][nt][r]);
      }
    }
  }
}

// ===========================================================================
extern "C" void kernel_launch(void* const* d_in, const int* in_sizes, int n_in,
                              void* d_out, int out_size, void* d_ws, size_t ws_size,
                              hipStream_t stream) {
  const float* xa = (const float*)d_in[0];
  const float* xm = (const float*)d_in[1];
  const float* Wih_1a = (const float*)d_in[2];
  const float* Whh_1a = (const float*)d_in[3];
  const float* bih_1a = (const float*)d_in[4];
  const float* bhh_1a = (const float*)d_in[5];
  const float* Wih_2a = (const float*)d_in[6];
  const float* Whh_2a = (const float*)d_in[7];
  const float* bih_2a = (const float*)d_in[8];
  const float* bhh_2a = (const float*)d_in[9];
  const float* Wih_1m = (const float*)d_in[10];
  const float* Whh_1m = (const float*)d_in[11];
  const float* bih_1m = (const float*)d_in[12];
  const float* bhh_1m = (const float*)d_in[13];
  const float* Wih_2m = (const float*)d_in[14];
  const float* Whh_2m = (const float*)d_in[15];
  const float* bih_2m = (const float*)d_in[16];
  const float* bhh_2m = (const float*)d_in[17];
  const float* Wg = (const float*)d_in[18];
  const float* bg = (const float*)d_in[19];
  const float* Wa = (const float*)d_in[20];
  const float* ba = (const float*)d_in[21];
  const float* Wm = (const float*)d_in[22];
  const float* bm = (const float*)d_in[23];

  char* ws = (char*)d_ws;
  const size_t MB = 1024ull * 1024;
  if (ws_size < 138 * MB) return;  // fail visibly

  f16* x16a    = (f16*)(ws + 0 * MB);     // dead after GEMM A
  f16* x16m    = (f16*)(ws + 8 * MB);     // dead after GEMM A
  f16* W1ih16a = (f16*)(ws + 16 * MB);    // dead after GEMM A
  f16* W1ih16m = (f16*)(ws + 32 * MB);    // dead after GEMM A
  f16* W1p_a   = (f16*)(ws + 48 * MB);
  f16* W1p_m   = (f16*)(ws + 56 * MB);
  f16* W2p_a   = (f16*)(ws + 64 * MB);
  f16* W2p_m   = (f16*)(ws + 80 * MB);
  f16* Wg16    = (f16*)(ws + 96 * MB);
  f16* Wa16    = (f16*)(ws + 100 * MB);
  f16* Wm16    = (f16*)(ws + 102 * MB);
  f16* G0a     = (f16*)(ws + 104 * MB);
  f16* G0m     = (f16*)(ws + 120 * MB);
  unsigned* flags1 = (unsigned*)(ws + 136 * MB);            // 32 KB
  unsigned* flags2 = (unsigned*)(ws + 136 * MB + 32768);    // 32 KB
  // aliases over GEMM-A-dead regions:
  f16* HaHm    = (f16*)(ws + 0 * MB);     // 8 MB over x16a
  f16* H1h     = (f16*)(ws + 8 * MB);     // 8 MB over x16m
  f16* h2c     = (f16*)(ws + 16 * MB);    // 8 MB over W1ih16a

  dim3 B256(256);
  k_cvt_all<<<28672, B256, 0, stream>>>(xa, x16a, xm, x16m, Wih_1a, W1ih16a,
                                        Wih_1m, W1ih16m, Wg, Wg16, Wa, Wa16,
                                        Wm, Wm16);
  k_packw1<<<dim3(2048, 2), B256, 0, stream>>>(Whh_1a, Whh_1m, W1p_a, W1p_m);
  k_packw2<<<dim3(4096, 2), B256, 0, stream>>>(Wih_2a, Whh_2a, Wih_2m, Whh_2m,
                                               W2p_a, W2p_m);
  hipMemsetAsync(flags1, 0, 65536, stream);   // flags1 + flags2

  // GEMM A: G0 = x @ Wih_1^T + (bih_1 + bhh_1)
  k_igemm<32, 2048><<<dim3(16, 32, 2), B256, 0, stream>>>(
      x16a, x16m, W1ih16a, W1ih16m, bih_1a, bhh_1a, bih_1m, bhh_1m, G0a, G0m);

  // dataflow scan (both cells, both streams)
  k_scan2<<<256, dim3(512), 0, stream>>>(
      W1p_a, W1p_m, W2p_a, W2p_m, G0a, G0m,
      bih_2a, bhh_2a, bih_2m, bhh_2m, H1h, h2c, HaHm, flags1, flags2);

  k_fusion<<<dim3(16, 16), B256, 0, stream>>>(HaHm, Wg16, Wa16, Wm16, bg, ba,
                                              bm, (float*)d_out);
}